// Round 2
// baseline (512.465 us; speedup 1.0000x reference)
//
#include <hip/hip_runtime.h>
#include <cstdint>
#include <cstddef>

#define BATCH  8192
#define IN_N   256
#define OUT_N  256
#define LAT_N  128
#define SLABS  129                 // 128 latent slabs + 1 bw slab
#define KT     (SLABS * IN_N)      // 33024 = W2T row length in elements
#define SPLITK 8
#define PSTRIDE 2097152            // BATCH*OUT_N elems per partial slice

typedef _Float16 h8 __attribute__((ext_vector_type(8)));
typedef _Float16 h4 __attribute__((ext_vector_type(4)));
typedef float    f16v __attribute__((ext_vector_type(16)));

// ws layout (bytes) — total 56,770,560 (identical to round-1 proven size)
#define WS_W2T   0                 // 256*33024*2 = 16,908,288
#define WS_XH    16908288          // 8192*256*2 = 4,194,304
#define WS_LT    21102592          // 129*8192*2 = 2,113,536
#define WS_PARTS 23216128          // 8 * 2097152 * 2 = 33,554,432 (f16 partials)

// ---------------- K1: W2T[o][k] = f16( k<32768 ? Ww[k*256+o] : bw[(k-32768)*256+o] )
// 16B/lane reads, LDS transpose (2-way bank aliasing only = free), 16B h8 writes.
__global__ void k_transpose(const float* __restrict__ Ww, const float* __restrict__ bw,
                            _Float16* __restrict__ W2T) {
    __shared__ float tile[64][65];
    const int k0 = blockIdx.x * 64;    // 516 tiles along k (512 Ww + 4 bw; no straddle)
    const int o0 = blockIdx.y * 64;    // 4 tiles along o
    const int t  = threadIdx.x;        // 256 threads
    const float* src; int kbase;
    if (k0 < LAT_N * IN_N) { src = Ww; kbase = k0; }
    else                   { src = bw; kbase = k0 - LAT_N * IN_N; }
#pragma unroll
    for (int j = 0; j < 4; ++j) {
        int idx = j * 256 + t;         // 0..1023
        int k = idx >> 4;              // 0..63
        int oc = (idx & 15) * 4;
        const float4 v = *(const float4*)(src + (size_t)(kbase + k) * 256 + o0 + oc);
        tile[k][oc + 0] = v.x; tile[k][oc + 1] = v.y;
        tile[k][oc + 2] = v.z; tile[k][oc + 3] = v.w;
    }
    __syncthreads();
#pragma unroll
    for (int j = 0; j < 2; ++j) {
        int idx = j * 256 + t;         // 0..511
        int o_r = idx >> 3;            // 0..63
        int k8 = (idx & 7) * 8;
        h8 pk;
#pragma unroll
        for (int i2 = 0; i2 < 8; ++i2) pk[i2] = (_Float16)tile[k8 + i2][o_r];
        *(h8*)(W2T + (size_t)(o0 + o_r) * KT + k0 + k8) = pk;
    }
}

// ---------------- K2 (fused): x->f16, latent->LT[l][b] (+ones row), bias->parts slice 0 (f16)
__global__ void k_prep(const float* __restrict__ x, const float* __restrict__ latent,
                       const float* __restrict__ Wb, const float* __restrict__ bb,
                       _Float16* __restrict__ Xh, _Float16* __restrict__ LT,
                       _Float16* __restrict__ part0) {
    __shared__ float lat[8][128];
    const int bid = blockIdx.x;
    const int t = threadIdx.x;
    if (bid < 2048) {                       // x: 2M elems, 4/thread
        int i = (bid * 256 + t) * 4;
        float4 v = *(const float4*)(x + i);
        h4 o;
        o[0] = (_Float16)v.x; o[1] = (_Float16)v.y;
        o[2] = (_Float16)v.z; o[3] = (_Float16)v.w;
        *(h4*)(Xh + i) = o;
    } else if (bid < 6144) {                // latent transpose: 1M elems
        int i = (bid - 2048) * 256 + t;
        int b = i >> 7, l = i & 127;
        LT[(size_t)l * BATCH + b] = (_Float16)latent[i];
    } else if (bid < 6176) {                // ones row
        int b = (bid - 6144) * 256 + t;
        LT[(size_t)LAT_N * BATCH + b] = (_Float16)1.0f;
    } else {                                // bias: part0[b][o] = latent[b]·Wb[:,o] + bb[o]
        const int b0 = (bid - 6176) * 8;    // 1024 blocks
#pragma unroll
        for (int j = 0; j < 4; ++j) {
            int idx = t + 256 * j;          // 0..1023
            int rr = idx >> 7, l = idx & 127;
            lat[rr][l] = latent[(size_t)(b0 + rr) * 128 + l];
        }
        __syncthreads();
        const int o = t;
        float acc[8];
        float bbv = bb[o];
#pragma unroll
        for (int rr = 0; rr < 8; ++rr) acc[rr] = bbv;
        for (int l = 0; l < 128; ++l) {
            float w = Wb[l * 256 + o];
#pragma unroll
            for (int rr = 0; rr < 8; ++rr) acc[rr] += lat[rr][l] * w;
        }
#pragma unroll
        for (int rr = 0; rr < 8; ++rr) part0[(size_t)(b0 + rr) * 256 + o] = (_Float16)acc[rr];
    }
}

// ---------------- K3: main GEMM. Block: 128 rows x 256 cols, split-K=8 over slabs.
// A (x) in LDS (swizzled, loaded once, barrier-free K loop); B (W2T) streamed global->VGPR.
// Grid 512 = 2 blocks/CU = 2 waves/SIMD (TLP to hide L2 latency on B loads).
__global__ __launch_bounds__(256, 2) void k_gemm(const _Float16* __restrict__ W2T,
                                                 const _Float16* __restrict__ Xh,
                                                 const _Float16* __restrict__ LT,
                                                 _Float16* __restrict__ parts) {
    __shared__ _Float16 Xs[128 * 256];      // 64 KB

    const int bid   = blockIdx.x;           // 512 blocks
    const int m_blk = bid >> 3;
    const int ks    = bid & 7;
    const int m0    = m_blk * 128;
    const int slab0 = (ks == 0) ? 0 : 16 * ks + 1;
    const int nslab = (ks == 0) ? 17 : 16;

    const int tid = threadIdx.x, wid = tid >> 6, lane = tid & 63;
    const int l32 = lane & 31, khalf = lane >> 5;

    // ---- stage X tile into LDS with 16B-granule XOR swizzle (granule g stored at slot g^(m&7))
    for (int j = 0; j < 16; ++j) {
        int G = j * 256 + tid;              // 4096 granules total
        int m = G >> 5, gp = G & 31;
        int g = gp ^ (m & 7);
        h8 v = *(const h8*)(Xh + (size_t)(m0 + m) * IN_N + g * 8);
        *(h8*)(Xs + m * IN_N + gp * 8) = v;
    }
    __syncthreads();

    // per-lane rows (A side): m = t*32 + l32
    int mrow[4], m7[4], pbase[4], m6[4];
#pragma unroll
    for (int t = 0; t < 4; ++t) {
        mrow[t]  = t * 32 + l32;
        m7[t]    = mrow[t] & 7;
        m6[t]    = m7[t] & 6;
        pbase[t] = mrow[t] * IN_N + (khalf ^ (m7[t] & 1)) * 8;
    }

    // latent scalars for this block's rows
    const _Float16* ltp = LT + (size_t)slab0 * BATCH + m0;
    _Float16 s_cur[4], s_nxt[4];
#pragma unroll
    for (int t = 0; t < 4; ++t) s_cur[t] = ltp[mrow[t]];

    // B pointers: cols n = wid*64 + u*32 + l32, k-contiguous
    const _Float16* bp0 = W2T + (size_t)(wid * 64 + 0 * 32 + l32) * KT + (size_t)slab0 * IN_N + khalf * 8;
    const _Float16* bp1 = W2T + (size_t)(wid * 64 + 1 * 32 + l32) * KT + (size_t)slab0 * IN_N + khalf * 8;

    f16v acc[4][2];
#pragma unroll
    for (int t = 0; t < 4; ++t)
#pragma unroll
        for (int u = 0; u < 2; ++u)
#pragma unroll
            for (int r = 0; r < 16; ++r) acc[t][u][r] = 0.0f;

    for (int sl = 0; sl < nslab; ++sl) {
        if (sl) {
#pragma unroll
            for (int t = 0; t < 4; ++t) s_cur[t] = s_nxt[t];
        }
        if (sl + 1 < nslab) {
            const _Float16* p = ltp + (size_t)(sl + 1) * BATCH;
#pragma unroll
            for (int t = 0; t < 4; ++t) s_nxt[t] = p[mrow[t]];
        }
        h8 s8[4];
#pragma unroll
        for (int t = 0; t < 4; ++t) {
            _Float16 s = s_cur[t];
            s8[t][0]=s; s8[t][1]=s; s8[t][2]=s; s8[t][3]=s;
            s8[t][4]=s; s8[t][5]=s; s8[t][6]=s; s8[t][7]=s;
        }
        const _Float16* b0p = bp0 + (size_t)sl * IN_N;
        const _Float16* b1p = bp1 + (size_t)sl * IN_N;
#pragma unroll
        for (int ks16 = 0; ks16 < 16; ++ks16) {
            h8 b0 = *(const h8*)(b0p + ks16 * 16);
            h8 b1 = *(const h8*)(b1p + ks16 * 16);
            h8 a[4];
#pragma unroll
            for (int t = 0; t < 4; ++t) {
                int off = pbase[t] + ((ks16 * 2) ^ m6[t]) * 8;
                h8 xv = *(const h8*)(Xs + off);
                a[t] = xv * s8[t];
            }
#pragma unroll
            for (int t = 0; t < 4; ++t) {
                acc[t][0] = __builtin_amdgcn_mfma_f32_32x32x16_f16(a[t], b0, acc[t][0], 0, 0, 0);
                acc[t][1] = __builtin_amdgcn_mfma_f32_32x32x16_f16(a[t], b1, acc[t][1], 0, 0, 0);
            }
        }
    }

    // epilogue: write f16 partials; split 0 accumulates onto pre-written bias
    _Float16* dst = parts + (size_t)ks * PSTRIDE;
#pragma unroll
    for (int t = 0; t < 4; ++t) {
        int rowb = m0 + t * 32;
#pragma unroll
        for (int u = 0; u < 2; ++u) {
            int col = wid * 64 + u * 32 + l32;
#pragma unroll
            for (int r = 0; r < 16; ++r) {
                int row = rowb + (r & 3) + 8 * (r >> 2) + 4 * khalf;
                size_t off = (size_t)row * OUT_N + col;
                float v = acc[t][u][r];
                if (ks == 0) v += (float)dst[off];
                dst[off] = (_Float16)v;
            }
        }
    }
}

// ---------------- K4: out = sum of 8 f16 partials
__global__ void k_reduce(const _Float16* __restrict__ parts, float* __restrict__ out) {
    int i = (blockIdx.x * 256 + threadIdx.x) * 4;
    float s0 = 0.f, s1 = 0.f, s2 = 0.f, s3 = 0.f;
#pragma unroll
    for (int p = 0; p < SPLITK; ++p) {
        h4 v = *(const h4*)(parts + (size_t)p * PSTRIDE + i);
        s0 += (float)v[0]; s1 += (float)v[1]; s2 += (float)v[2]; s3 += (float)v[3];
    }
    float4 o = make_float4(s0, s1, s2, s3);
    *(float4*)(out + i) = o;
}

extern "C" void kernel_launch(void* const* d_in, const int* in_sizes, int n_in,
                              void* d_out, int out_size, void* d_ws, size_t ws_size,
                              hipStream_t stream) {
    const float* x      = (const float*)d_in[0];
    const float* latent = (const float*)d_in[1];
    const float* Ww     = (const float*)d_in[2];
    const float* bw     = (const float*)d_in[3];
    const float* Wb     = (const float*)d_in[4];
    const float* bb     = (const float*)d_in[5];

    char* ws = (char*)d_ws;
    _Float16* W2T   = (_Float16*)(ws + WS_W2T);
    _Float16* Xh    = (_Float16*)(ws + WS_XH);
    _Float16* LT    = (_Float16*)(ws + WS_LT);
    _Float16* parts = (_Float16*)(ws + WS_PARTS);
    float*    out   = (float*)d_out;

    k_transpose<<<dim3(516, 4), 256, 0, stream>>>(Ww, bw, W2T);
    k_prep<<<7200, 256, 0, stream>>>(x, latent, Wb, bb, Xh, LT, parts);
    k_gemm<<<512, 256, 0, stream>>>(W2T, Xh, LT, parts);
    k_reduce<<<2048, 256, 0, stream>>>(parts, out);
}

// Round 3
// 378.377 us; speedup vs baseline: 1.3544x; 1.3544x over previous
//
#include <hip/hip_runtime.h>
#include <cstdint>
#include <cstddef>

#define BATCH  8192
#define IN_N   256
#define OUT_N  256
#define LAT_N  128
#define SLABS  129                 // 128 latent slabs + 1 bw slab
#define KT     (SLABS * IN_N)      // 33024 = W2T row length in elements
#define SPLITK 8
#define PSTRIDE 2097152            // BATCH*OUT_N elems per partial slice

typedef _Float16 h8 __attribute__((ext_vector_type(8)));
typedef _Float16 h4 __attribute__((ext_vector_type(4)));
typedef float    f16v __attribute__((ext_vector_type(16)));

// ws layout (bytes) — total 56,770,560
#define WS_W2T   0                 // 256*33024*2 = 16,908,288
#define WS_XH    16908288          // 8192*256*2 = 4,194,304
#define WS_LT    21102592          // 129*8192*2 = 2,113,536
#define WS_PARTS 23216128          // 8 * 2097152 * 2 = 33,554,432 (f16 partials)

// ---------------- K1: W2T[o][k] = f16( k<32768 ? Ww[k*256+o] : bw[(k-32768)*256+o] )
__global__ void k_transpose(const float* __restrict__ Ww, const float* __restrict__ bw,
                            _Float16* __restrict__ W2T) {
    __shared__ float tile[64][65];
    const int k0 = blockIdx.x * 64;    // 516 tiles along k (512 Ww + 4 bw; no straddle)
    const int o0 = blockIdx.y * 64;    // 4 tiles along o
    const int t  = threadIdx.x;        // 256 threads
    const float* src; int kbase;
    if (k0 < LAT_N * IN_N) { src = Ww; kbase = k0; }
    else                   { src = bw; kbase = k0 - LAT_N * IN_N; }
#pragma unroll
    for (int j = 0; j < 4; ++j) {
        int idx = j * 256 + t;         // 0..1023
        int k = idx >> 4;              // 0..63
        int oc = (idx & 15) * 4;
        const float4 v = *(const float4*)(src + (size_t)(kbase + k) * 256 + o0 + oc);
        tile[k][oc + 0] = v.x; tile[k][oc + 1] = v.y;
        tile[k][oc + 2] = v.z; tile[k][oc + 3] = v.w;
    }
    __syncthreads();
#pragma unroll
    for (int j = 0; j < 2; ++j) {
        int idx = j * 256 + t;         // 0..511
        int o_r = idx >> 3;            // 0..63
        int k8 = (idx & 7) * 8;
        h8 pk;
#pragma unroll
        for (int i2 = 0; i2 < 8; ++i2) pk[i2] = (_Float16)tile[k8 + i2][o_r];
        *(h8*)(W2T + (size_t)(o0 + o_r) * KT + k0 + k8) = pk;
    }
}

// ---------------- K2 (fused): x->f16, latent->LT[l][b] (+ones row), bias->parts slice 0 (f16)
__global__ void k_prep(const float* __restrict__ x, const float* __restrict__ latent,
                       const float* __restrict__ Wb, const float* __restrict__ bb,
                       _Float16* __restrict__ Xh, _Float16* __restrict__ LT,
                       _Float16* __restrict__ part0) {
    __shared__ float lat[8][128];
    const int bid = blockIdx.x;
    const int t = threadIdx.x;
    if (bid < 2048) {                       // x: 2M elems, 4/thread
        int i = (bid * 256 + t) * 4;
        float4 v = *(const float4*)(x + i);
        h4 o;
        o[0] = (_Float16)v.x; o[1] = (_Float16)v.y;
        o[2] = (_Float16)v.z; o[3] = (_Float16)v.w;
        *(h4*)(Xh + i) = o;
    } else if (bid < 6144) {                // latent transpose: 1M elems
        int i = (bid - 2048) * 256 + t;
        int b = i >> 7, l = i & 127;
        LT[(size_t)l * BATCH + b] = (_Float16)latent[i];
    } else if (bid < 6176) {                // ones row
        int b = (bid - 6144) * 256 + t;
        LT[(size_t)LAT_N * BATCH + b] = (_Float16)1.0f;
    } else {                                // bias: part0[b][o] = latent[b]·Wb[:,o] + bb[o]
        const int b0 = (bid - 6176) * 8;    // 1024 blocks
#pragma unroll
        for (int j = 0; j < 4; ++j) {
            int idx = t + 256 * j;          // 0..1023
            int rr = idx >> 7, l = idx & 127;
            lat[rr][l] = latent[(size_t)(b0 + rr) * 128 + l];
        }
        __syncthreads();
        const int o = t;
        float acc[8];
        float bbv = bb[o];
#pragma unroll
        for (int rr = 0; rr < 8; ++rr) acc[rr] = bbv;
        for (int l = 0; l < 128; ++l) {
            float w = Wb[l * 256 + o];
#pragma unroll
            for (int rr = 0; rr < 8; ++rr) acc[rr] += lat[rr][l] * w;
        }
#pragma unroll
        for (int rr = 0; rr < 8; ++rr) part0[(size_t)(b0 + rr) * 256 + o] = (_Float16)acc[rr];
    }
}

// ---------------- K3: main GEMM. Block: 128 rows x 256 cols, split-K=8 over slabs.
// A (x) in LDS (swizzled, loaded once, barrier-free K loop); B (W2T) streamed global->VGPR.
// Grid 512 = 2 blocks/CU. NOTE: launch_bounds min-waves MUST stay 1 — at (256,2) the
// allocator caps at 128 VGPR and spills the 128-reg accumulator (R2: 680 MB FETCH_SIZE).
// At 248 VGPR the HW runs 2 waves/SIMD anyway (pool ~512/SIMD), LDS 2x64KB <= 160KB.
__global__ __launch_bounds__(256, 1) void k_gemm(const _Float16* __restrict__ W2T,
                                                 const _Float16* __restrict__ Xh,
                                                 const _Float16* __restrict__ LT,
                                                 _Float16* __restrict__ parts) {
    __shared__ _Float16 Xs[128 * 256];      // 64 KB

    const int bid   = blockIdx.x;           // 512 blocks
    const int m_blk = bid >> 3;
    const int ks    = bid & 7;              // == XCD id under round-robin dispatch -> per-XCD
    const int m0    = m_blk * 128;          //    L2 sees only its 2.1 MB slab slice
    const int slab0 = (ks == 0) ? 0 : 16 * ks + 1;
    const int nslab = (ks == 0) ? 17 : 16;

    const int tid = threadIdx.x, wid = tid >> 6, lane = tid & 63;
    const int l32 = lane & 31, khalf = lane >> 5;

    // ---- stage X tile into LDS with 16B-granule XOR swizzle (granule g stored at slot g^(m&7))
    for (int j = 0; j < 16; ++j) {
        int G = j * 256 + tid;              // 4096 granules total
        int m = G >> 5, gp = G & 31;
        int g = gp ^ (m & 7);
        h8 v = *(const h8*)(Xh + (size_t)(m0 + m) * IN_N + g * 8);
        *(h8*)(Xs + m * IN_N + gp * 8) = v;
    }
    __syncthreads();

    // per-lane rows (A side): m = t*32 + l32
    int mrow[4], m7[4], pbase[4], m6[4];
#pragma unroll
    for (int t = 0; t < 4; ++t) {
        mrow[t]  = t * 32 + l32;
        m7[t]    = mrow[t] & 7;
        m6[t]    = m7[t] & 6;
        pbase[t] = mrow[t] * IN_N + (khalf ^ (m7[t] & 1)) * 8;
    }

    // latent scalars for this block's rows
    const _Float16* ltp = LT + (size_t)slab0 * BATCH + m0;
    _Float16 s_cur[4], s_nxt[4];
#pragma unroll
    for (int t = 0; t < 4; ++t) s_cur[t] = ltp[mrow[t]];

    // B pointers: cols n = wid*64 + u*32 + l32, k-contiguous
    const _Float16* bp0 = W2T + (size_t)(wid * 64 + 0 * 32 + l32) * KT + (size_t)slab0 * IN_N + khalf * 8;
    const _Float16* bp1 = W2T + (size_t)(wid * 64 + 1 * 32 + l32) * KT + (size_t)slab0 * IN_N + khalf * 8;

    f16v acc[4][2];
#pragma unroll
    for (int t = 0; t < 4; ++t)
#pragma unroll
        for (int u = 0; u < 2; ++u)
#pragma unroll
            for (int r = 0; r < 16; ++r) acc[t][u][r] = 0.0f;

    for (int sl = 0; sl < nslab; ++sl) {
        if (sl) {
#pragma unroll
            for (int t = 0; t < 4; ++t) s_cur[t] = s_nxt[t];
        }
        if (sl + 1 < nslab) {
            const _Float16* p = ltp + (size_t)(sl + 1) * BATCH;
#pragma unroll
            for (int t = 0; t < 4; ++t) s_nxt[t] = p[mrow[t]];
        }
        h8 s8[4];
#pragma unroll
        for (int t = 0; t < 4; ++t) {
            _Float16 s = s_cur[t];
            s8[t][0]=s; s8[t][1]=s; s8[t][2]=s; s8[t][3]=s;
            s8[t][4]=s; s8[t][5]=s; s8[t][6]=s; s8[t][7]=s;
        }
        const _Float16* b0p = bp0 + (size_t)sl * IN_N;
        const _Float16* b1p = bp1 + (size_t)sl * IN_N;
#pragma unroll
        for (int ks16 = 0; ks16 < 16; ++ks16) {
            h8 b0 = *(const h8*)(b0p + ks16 * 16);
            h8 b1 = *(const h8*)(b1p + ks16 * 16);
            h8 a[4];
#pragma unroll
            for (int t = 0; t < 4; ++t) {
                int off = pbase[t] + ((ks16 * 2) ^ m6[t]) * 8;
                h8 xv = *(const h8*)(Xs + off);
                a[t] = xv * s8[t];
            }
#pragma unroll
            for (int t = 0; t < 4; ++t) {
                acc[t][0] = __builtin_amdgcn_mfma_f32_32x32x16_f16(a[t], b0, acc[t][0], 0, 0, 0);
                acc[t][1] = __builtin_amdgcn_mfma_f32_32x32x16_f16(a[t], b1, acc[t][1], 0, 0, 0);
            }
        }
    }

    // epilogue: write f16 partials; split 0 accumulates onto pre-written bias
    _Float16* dst = parts + (size_t)ks * PSTRIDE;
#pragma unroll
    for (int t = 0; t < 4; ++t) {
        int rowb = m0 + t * 32;
#pragma unroll
        for (int u = 0; u < 2; ++u) {
            int col = wid * 64 + u * 32 + l32;
#pragma unroll
            for (int r = 0; r < 16; ++r) {
                int row = rowb + (r & 3) + 8 * (r >> 2) + 4 * khalf;
                size_t off = (size_t)row * OUT_N + col;
                float v = acc[t][u][r];
                if (ks == 0) v += (float)dst[off];
                dst[off] = (_Float16)v;
            }
        }
    }
}

// ---------------- K4: out = sum of 8 f16 partials
__global__ void k_reduce(const _Float16* __restrict__ parts, float* __restrict__ out) {
    int i = (blockIdx.x * 256 + threadIdx.x) * 4;
    float s0 = 0.f, s1 = 0.f, s2 = 0.f, s3 = 0.f;
#pragma unroll
    for (int p = 0; p < SPLITK; ++p) {
        h4 v = *(const h4*)(parts + (size_t)p * PSTRIDE + i);
        s0 += (float)v[0]; s1 += (float)v[1]; s2 += (float)v[2]; s3 += (float)v[3];
    }
    float4 o = make_float4(s0, s1, s2, s3);
    *(float4*)(out + i) = o;
}

extern "C" void kernel_launch(void* const* d_in, const int* in_sizes, int n_in,
                              void* d_out, int out_size, void* d_ws, size_t ws_size,
                              hipStream_t stream) {
    const float* x      = (const float*)d_in[0];
    const float* latent = (const float*)d_in[1];
    const float* Ww     = (const float*)d_in[2];
    const float* bw     = (const float*)d_in[3];
    const float* Wb     = (const float*)d_in[4];
    const float* bb     = (const float*)d_in[5];

    char* ws = (char*)d_ws;
    _Float16* W2T   = (_Float16*)(ws + WS_W2T);
    _Float16* Xh    = (_Float16*)(ws + WS_XH);
    _Float16* LT    = (_Float16*)(ws + WS_LT);
    _Float16* parts = (_Float16*)(ws + WS_PARTS);
    float*    out   = (float*)d_out;

    k_transpose<<<dim3(516, 4), 256, 0, stream>>>(Ww, bw, W2T);
    k_prep<<<7200, 256, 0, stream>>>(x, latent, Wb, bb, Xh, LT, parts);
    k_gemm<<<512, 256, 0, stream>>>(W2T, Xh, LT, parts);
    k_reduce<<<2048, 256, 0, stream>>>(parts, out);
}